// Round 3
// baseline (162.922 us; speedup 1.0000x reference)
//
#include <hip/hip_runtime.h>
#include <hip/hip_bf16.h>
#include <stdint.h>

// Problem constants
#define NROWS 4096
#define NCLS  97
#define EMB   768
#define KTOT  49152                 // EMB * 64
#define OUT_ELEMS (NROWS * NCLS)    // 397312
#define E_ELEMS  (NROWS * EMB)      // 3,145,728
#define NK32  (KTOT / 32)           // 1536 k-chunks of 32
#define WT_BYTES ((size_t)NK32 * 128 * 64)   // 12,582,912 (Wt: [kc][c<128][32] bf16)
#define EB_BYTES ((size_t)E_ELEMS * 2)       // 6,291,456

typedef __attribute__((ext_vector_type(8)))  short short8;
typedef __attribute__((ext_vector_type(4)))  float floatx4;
typedef __bf16 bf16x2 __attribute__((ext_vector_type(2)));
typedef __bf16 bf16x4 __attribute__((ext_vector_type(4)));
typedef __bf16 bf16x8 __attribute__((ext_vector_type(8)));

__device__ __forceinline__ uint32_t pkmul(uint32_t a, uint32_t b) {
  bf16x2 x = __builtin_bit_cast(bf16x2, a);
  bf16x2 y = __builtin_bit_cast(bf16x2, b);
  bf16x2 r = x * y;
  return __builtin_bit_cast(uint32_t, r);
}

__device__ __forceinline__ uint4 cvt8(float4 a, float4 b) {
  bf16x8 v;
  v[0] = (__bf16)a.x; v[1] = (__bf16)a.y; v[2] = (__bf16)a.z; v[3] = (__bf16)a.w;
  v[4] = (__bf16)b.x; v[5] = (__bf16)b.y; v[6] = (__bf16)b.z; v[7] = (__bf16)b.w;
  return __builtin_bit_cast(uint4, v);
}

__device__ __forceinline__ uint2 cvt4(float4 a) {
  bf16x4 v;
  v[0] = (__bf16)a.x; v[1] = (__bf16)a.y; v[2] = (__bf16)a.z; v[3] = (__bf16)a.w;
  return __builtin_bit_cast(uint2, v);
}

// Prep: build Wt (W transposed into MFMA B-fragment order, bf16, classes
// padded to 128 with zeros) and optional bf16 mirrors of b1/b2.
// Wt 16B-chunk t: eo=t&3 (8-elem octet), c=(t>>2)&127, kc=t>>9:
//   Wt byte addr = kc*8192 + c*64 + eo*16  <-> W[c][kc*32 + eo*8 .. +7]
__global__ void prep(const float* __restrict__ W,
                     const float* __restrict__ b1,
                     const float* __restrict__ b2,
                     uint4* __restrict__ wt,
                     uint4* __restrict__ b1b,
                     uint4* __restrict__ b2b,
                     int nmax)
{
  const int nwt = NK32 * 128 * 4;      // 786,432
  const int nE8 = E_ELEMS / 8;         // 393,216
  int t = blockIdx.x * blockDim.x + threadIdx.x;
  if (t >= nmax) return;
  if (t < nwt) {
    int eo = t & 3;
    int c  = (t >> 2) & 127;
    int kc = t >> 9;
    uint4 v = uint4{0u, 0u, 0u, 0u};
    if (c < NCLS) {
      const float4* p = (const float4*)(W + (size_t)c * KTOT + kc * 32 + eo * 8);
      v = cvt8(p[0], p[1]);
    }
    wt[t] = v;
  } else if (t < nwt + nE8) {
    int i = t - nwt;
    const float4* p = (const float4*)b1 + (size_t)2 * i;
    b1b[i] = cvt8(p[0], p[1]);
  } else {
    int i = t - nwt - nE8;
    const float4* p = (const float4*)b2 + (size_t)2 * i;
    b2b[i] = cvt8(p[0], p[1]);
  }
}

// Fused on-the-fly-A GEMM, R13: occupancy is REGISTER-capped, not grid-capped.
// Evidence: acc[4][4] = 64 AGPRs live outside VGPR_Count(112); total ~176/wave
// -> 2 waves/SIMD on gfx950's unified RF (R10/R12 both measured ~18-19% occ;
// R11 at 96 total measured 40%). R13: __launch_bounds__(256,3) caps total at
// 168 (arch <= 104) for 3 waves/SIMD; b1c shrunk uint4->uint2 halves to give
// the allocator the needed ~8 regs. Grid must supply 3 blocks/CU: KS=24 ->
// 768 blocks. klen=2048 = exactly one kblk per block (b2c loaded once).
// rt=4 kept: each Wt fragment feeds 4 MFMAs (R11 showed halving this doubles
// Wt traffic and loses). ct==3 tile (cols 112..127) is zero class-pad:
// chalf==1 waves skip its load+MFMA (wave-uniform).
// MFMA 16x16x32 bf16 verified triple:
//   A: lane l holds A[m=l&15][k=(l>>4)*8+j]; B: W[c=l&15][k=(l>>4)*8+j]
//   D: lane l, reg r: col(c)=l&15, row(n)=(l>>4)*4+r
// Grid (KS, 32): x = k-slice (XCD co-location: linear id % 8 = x % 8 when
// gridDim.x%8==0 -> same Wt slice stays in one XCD's L2), y = 128-row tile.
template<bool BMIR>
__global__ __launch_bounds__(256, 3)
void bilinear_main(const void* __restrict__ b1p,
                   const void* __restrict__ b2p,
                   const char* __restrict__ Wt,
                   const float* __restrict__ biasg,
                   float* __restrict__ P,
                   float* __restrict__ outd,
                   int klen)
{
  const int tid  = threadIdx.x;
  const int w    = tid >> 6;
  const int l    = tid & 63;
  const int l15  = l & 15;
  const int quad = l >> 4;
  const int mhalf = w & 1;
  const int chalf = w >> 1;
  const bool cfull = (chalf == 0);   // chalf=1 waves skip ct==3 (zero pad)
  const int bm = blockIdx.y;
  const int k0 = blockIdx.x * klen;

  int nrow[4];
#pragma unroll
  for (int rt = 0; rt < 4; ++rt) nrow[rt] = bm * 128 + mhalf * 64 + rt * 16 + l15;

  // Lane-fixed Wt base for this block's k-range.
  const char* wtl = Wt + (size_t)(k0 >> 5) * 8192
                       + (chalf * 64 + l15) * 64 + quad * 16;

  floatx4 acc[4][4];
#pragma unroll
  for (int rt = 0; rt < 4; ++rt)
#pragma unroll
    for (int ct = 0; ct < 4; ++ct)
      acc[rt][ct] = floatx4{0.f, 0.f, 0.f, 0.f};

  uint4 b2c[4][2];   // bf16 b2[nrow[rt], kblk, kh*32+quad*8 .. +7]
  int cur_k = -1;
  const int nwin = klen >> 6;

  for (int gwin = 0; gwin < nwin; gwin += 8) {
    const int kap0 = k0 + (gwin << 6);
    const int kblk = kap0 >> 12;
    const int i0   = (kap0 >> 6) & 63;
    if (kblk != cur_k) {
      cur_k = kblk;
#pragma unroll
      for (int rt = 0; rt < 4; ++rt)
#pragma unroll
        for (int kh = 0; kh < 2; ++kh) {
          if (BMIR) {
            b2c[rt][kh] = *(const uint4*)((const char*)b2p +
                            (size_t)nrow[rt] * 1536 + kblk * 128 + kh * 64 + quad * 16);
          } else {
            const float* p = (const float*)b2p + (size_t)nrow[rt] * EMB +
                             kblk * 64 + kh * 32 + quad * 8;
            b2c[rt][kh] = cvt8(((const float4*)p)[0], ((const float4*)p)[1]);
          }
        }
    }

    // Two half-groups of 4 windows each; b1 scalars held as uint2 (4 bf16)
    // per rt instead of uint4 -> 8 fewer live VGPRs (funds 3 waves/SIMD).
#pragma unroll
    for (int ih = 0; ih < 2; ++ih) {
      uint2 b1h[4];
#pragma unroll
      for (int rt = 0; rt < 4; ++rt) {
        if (BMIR) {
          b1h[rt] = *(const uint2*)((const char*)b1p +
                       (size_t)nrow[rt] * 1536 + kblk * 128 + (i0 + ih * 4) * 2);
        } else {
          const float* p = (const float*)b1p + (size_t)nrow[rt] * EMB +
                           kblk * 64 + i0 + ih * 4;
          b1h[rt] = cvt4(((const float4*)p)[0]);
        }
      }

#pragma unroll
      for (int ii2 = 0; ii2 < 4; ++ii2) {
        const int iw = gwin + ih * 4 + ii2;
        // This window's Wt pointer: k-chunks iw*2 and iw*2+1.
        const char* pw = wtl + (size_t)iw * 16384;

        // b1 scalar for this window, broadcast to a bf16 pair.
        uint32_t s2[4];
#pragma unroll
        for (int rt = 0; rt < 4; ++rt) {
          uint32_t d = (&b1h[rt].x)[ii2 >> 1];
          uint32_t h = (ii2 & 1) ? (d >> 16) : (d & 0xffffu);
          s2[rt] = h | (h << 16);
        }

#pragma unroll
        for (int kh = 0; kh < 2; ++kh) {
          // Coalesced B-fragment loads (16B/lane from a 1KB-contig region);
          // ct==3 is the zero class-pad for chalf==1 -> skip (wave-uniform).
          short8 wf[4];
#pragma unroll
          for (int ct = 0; ct < 4; ++ct)
            if (ct < 3 || cfull)
              wf[ct] = __builtin_bit_cast(short8,
                         *(const uint4*)(pw + kh * 8192 + ct * 1024));
          // A fragments for this kh
          uint4 afr[4];
#pragma unroll
          for (int rt = 0; rt < 4; ++rt) {
            afr[rt].x = pkmul(s2[rt], b2c[rt][kh].x);
            afr[rt].y = pkmul(s2[rt], b2c[rt][kh].y);
            afr[rt].z = pkmul(s2[rt], b2c[rt][kh].z);
            afr[rt].w = pkmul(s2[rt], b2c[rt][kh].w);
          }
#pragma unroll
          for (int rt = 0; rt < 4; ++rt) {
            short8 af = __builtin_bit_cast(short8, afr[rt]);
#pragma unroll
            for (int ct = 0; ct < 4; ++ct)
              if (ct < 3 || cfull)
                acc[rt][ct] = __builtin_amdgcn_mfma_f32_16x16x32_bf16(
                                  af, wf[ct], acc[rt][ct], 0, 0, 0);
          }
        }
      }
    }
  }

  // Epilogue. D: col(c)=l15, row(n)=quad*4+r within each 16x16 tile.
  if (P) {
    float* Pb = P + (size_t)blockIdx.x * OUT_ELEMS;   // slice = blockIdx.x
#pragma unroll
    for (int rt = 0; rt < 4; ++rt)
#pragma unroll
      for (int ct = 0; ct < 4; ++ct) {
        const int c = chalf * 64 + ct * 16 + l15;
        if (c < NCLS) {
#pragma unroll
          for (int r = 0; r < 4; ++r) {
            const int row = bm * 128 + mhalf * 64 + rt * 16 + quad * 4 + r;
            Pb[(size_t)row * NCLS + c] = acc[rt][ct][r];
          }
        }
      }
  } else {
#pragma unroll
    for (int rt = 0; rt < 4; ++rt)
#pragma unroll
      for (int ct = 0; ct < 4; ++ct) {
        const int c = chalf * 64 + ct * 16 + l15;
        if (c < NCLS) {
          const float bv = biasg[c];
#pragma unroll
          for (int r = 0; r < 4; ++r) {
            const int row = bm * 128 + mhalf * 64 + rt * 16 + quad * 4 + r;
            outd[(size_t)row * NCLS + c] = acc[rt][ct][r] + bv;
          }
        }
      }
  }
}

// Sum KS partial slices + f32 bias -> f32 output. float4-vectorized.
// KS is a compile-time template arg so the accumulation loop fully unrolls
// (runtime bound left a dependent load->add chain, one L2 latency per slice).
template<int KSC>
__global__ void reduce_bias_t(const float* __restrict__ P,
                              const float* __restrict__ biasg,
                              float* __restrict__ out)
{
  int i = blockIdx.x * blockDim.x + threadIdx.x;
  const int n4 = OUT_ELEMS / 4;           // 99328
  if (i >= n4) return;
  int c0 = (i * 4) % NCLS;
  int c1 = c0 + 1 == NCLS ? 0 : c0 + 1;
  int c2 = c1 + 1 == NCLS ? 0 : c1 + 1;
  int c3 = c2 + 1 == NCLS ? 0 : c2 + 1;
  float4 s;
  s.x = biasg[c0]; s.y = biasg[c1]; s.z = biasg[c2]; s.w = biasg[c3];
  const float4* P4 = (const float4*)P;
#pragma unroll
  for (int t = 0; t < KSC; ++t) {
    float4 v = P4[(size_t)t * n4 + i];
    s.x += v.x; s.y += v.y; s.z += v.z; s.w += v.w;
  }
  ((float4*)out)[i] = s;
}

static void launch_reduce(int KS, const float* P, const float* bb, float* out,
                          hipStream_t stream) {
  const int nb = (OUT_ELEMS / 4 + 255) / 256;
  switch (KS) {
    case 24: reduce_bias_t<24><<<nb, 256, 0, stream>>>(P, bb, out); break;
    case 16: reduce_bias_t<16><<<nb, 256, 0, stream>>>(P, bb, out); break;
    case 12: reduce_bias_t<12><<<nb, 256, 0, stream>>>(P, bb, out); break;
    case 8:  reduce_bias_t<8><<<nb, 256, 0, stream>>>(P, bb, out);  break;
    case 6:  reduce_bias_t<6><<<nb, 256, 0, stream>>>(P, bb, out);  break;
    case 4:  reduce_bias_t<4><<<nb, 256, 0, stream>>>(P, bb, out);  break;
    case 3:  reduce_bias_t<3><<<nb, 256, 0, stream>>>(P, bb, out);  break;
    case 2:  reduce_bias_t<2><<<nb, 256, 0, stream>>>(P, bb, out);  break;
    default: reduce_bias_t<1><<<nb, 256, 0, stream>>>(P, bb, out);  break;
  }
}

extern "C" void kernel_launch(void* const* d_in, const int* in_sizes, int n_in,
                              void* d_out, int out_size, void* d_ws, size_t ws_size,
                              hipStream_t stream) {
  const float* b1f = (const float*)d_in[0];   // [4096,768] f32
  const float* b2f = (const float*)d_in[1];   // [4096,768] f32
  const float* Wf  = (const float*)d_in[2];   // [97, 49152] f32
  const float* bbf = (const float*)d_in[3];   // [97] f32
  float* out = (float*)d_out;

  const size_t resv_full = WT_BYTES + 2 * EB_BYTES;   // 25,165,824
  const size_t slice     = (size_t)OUT_ELEMS * 4;     // 1,589,248
  // klen = KTOT/KS must be a multiple of 512 -> KS divides 96.
  // KS=24 -> grid 768 blocks = 3 blocks/CU, matching __launch_bounds__(256,3).
  static const int cands[] = {24, 16, 12, 8, 6, 4, 3, 2, 1};
  const int NC = 9;

  // Workspace plan: [Wt | b1b | b2b | P] (full) or [Wt | P] (b from f32).
  int KS = 0; bool bmir = false;
  for (int i = 0; i < NC; ++i)
    if (resv_full + (size_t)cands[i] * slice <= ws_size) { KS = cands[i]; bmir = true; break; }
  if (!bmir)
    for (int i = 0; i < NC; ++i)
      if (WT_BYTES + (size_t)cands[i] * slice <= ws_size) { KS = cands[i]; break; }

  uint4* Wt  = (uint4*)d_ws;
  uint4* b1b = (uint4*)((char*)d_ws + WT_BYTES);
  uint4* b2b = (uint4*)((char*)d_ws + WT_BYTES + EB_BYTES);
  const int nwt = NK32 * 128 * 4;
  const int nE8 = E_ELEMS / 8;
  const int nprep = bmir ? (nwt + 2 * nE8) : nwt;

  prep<<<(nprep + 255) / 256, 256, 0, stream>>>(Wf, b1f, b2f, Wt, b1b, b2b, nprep);

  if (KS > 0) {
    float* P = (float*)((char*)d_ws + (bmir ? resv_full : WT_BYTES));
    if (bmir)
      bilinear_main<true><<<dim3(KS, 32), 256, 0, stream>>>(
          (const void*)b1b, (const void*)b2b, (const char*)Wt, bbf, P, nullptr, KTOT / KS);
    else
      bilinear_main<false><<<dim3(KS, 32), 256, 0, stream>>>(
          (const void*)b1f, (const void*)b2f, (const char*)Wt, bbf, P, nullptr, KTOT / KS);
    launch_reduce(KS, P, bbf, out, stream);
  } else {
    // Minimal-workspace fallback: single slice, direct f32 output.
    bilinear_main<false><<<dim3(1, 32), 256, 0, stream>>>(
        (const void*)b1f, (const void*)b2f, (const char*)Wt, bbf, nullptr, out, KTOT);
  }
}

// Round 5
// 152.805 us; speedup vs baseline: 1.0662x; 1.0662x over previous
//
#include <hip/hip_runtime.h>
#include <hip/hip_bf16.h>
#include <stdint.h>

// Problem constants
#define NROWS 4096
#define NCLS  97
#define EMB   768
#define KTOT  49152                 // EMB * 64
#define OUT_ELEMS (NROWS * NCLS)    // 397312
#define E_ELEMS  (NROWS * EMB)      // 3,145,728
#define NK32  (KTOT / 32)           // 1536 k-chunks of 32
#define WT_BYTES ((size_t)NK32 * 128 * 64)   // 12,582,912 (Wt: [kc][c<128][32] bf16)

typedef __attribute__((ext_vector_type(8)))  short short8;
typedef __attribute__((ext_vector_type(4)))  float floatx4;
typedef __bf16 bf16x2 __attribute__((ext_vector_type(2)));
typedef __bf16 bf16x8 __attribute__((ext_vector_type(8)));

__device__ __forceinline__ uint4 cvt8(float4 a, float4 b) {
  bf16x8 v;
  v[0] = (__bf16)a.x; v[1] = (__bf16)a.y; v[2] = (__bf16)a.z; v[3] = (__bf16)a.w;
  v[4] = (__bf16)b.x; v[5] = (__bf16)b.y; v[6] = (__bf16)b.z; v[7] = (__bf16)b.w;
  return __builtin_bit_cast(uint4, v);
}

// Pack two f32 into one dword of 2 bf16 (lo,hi). Compiler emits
// v_cvt_pk_bf16_f32 for this cast pair on gfx950 (m240: cast beats asm).
__device__ __forceinline__ uint32_t mkbf2(float lo, float hi) {
  bf16x2 v; v[0] = (__bf16)lo; v[1] = (__bf16)hi;
  return __builtin_bit_cast(uint32_t, v);
}

// Prep: build Wt only (W transposed into MFMA B-fragment order, bf16,
// classes padded to 128 with zeros). b1/b2 are consumed in f32 directly.
// Wt 16B-chunk t: eo=t&3 (8-elem octet), c=(t>>2)&127, kc=t>>9:
//   Wt byte addr = kc*8192 + c*64 + eo*16  <-> W[c][kc*32 + eo*8 .. +7]
__global__ void prep(const float* __restrict__ W, uint4* __restrict__ wt)
{
  const int nwt = NK32 * 128 * 4;      // 786,432
  int t = blockIdx.x * blockDim.x + threadIdx.x;
  if (t >= nwt) return;
  int eo = t & 3;
  int c  = (t >> 2) & 127;
  int kc = t >> 9;
  uint4 v = uint4{0u, 0u, 0u, 0u};
  if (c < NCLS) {
    const float4* p = (const float4*)(W + (size_t)c * KTOT + kc * 32 + eo * 8);
    v = cvt8(p[0], p[1]);
  }
  wt[t] = v;
}

// Fused on-the-fly-A GEMM, R14 (resubmit after infra failure; source audited:
// no dynamic reg indexing, loops terminate, all addresses in-bounds).
// Theory: kernel is VALU-BOUND on A-fragment build.
// R13 counters: 1962 cyc/window/SIMD; MFMA 543 cyc (28 x ~19.4 cyc/SIMD-pipe,
// matches MfmaUtil 27%); VALU 824 cyc = ~412 insts/window (VALUBusy 42%).
// Culprit: pkmul(bf16x2*bf16x2) is EMULATED (unpack->f32 mul->round back)
// plus s2 half-extract/shift/or packing: ~12 VALU per A-dword. 3rd wave
// (R13) bought nothing because VALU, not latency, is the limit.
// R14: A-fragments built in f32: b2 cached as f32 regs per kblk (64 VGPRs,
// amortized over 64 windows), b1 kept as f32 float4 (window scalar = free
// register select), per A-dword = 2 v_mul_f32 + 1 cvt_pk cast = 3 insts
// (~110 VALU/window vs 412). Costs ~64 regs -> 2 waves/SIMD by design
// (launch_bounds(256,2)); KS=16 -> grid 512 = exactly 2 blocks/CU, and
// halves P traffic vs KS=24. rt=4 kept (each Wt fragment feeds 4 MFMAs).
// ct==3 tile (cols 112..127) is zero class-pad: chalf==1 waves skip it.
// MFMA 16x16x32 bf16 verified triple:
//   A: lane l holds A[m=l&15][k=(l>>4)*8+j]; B: W[c=l&15][k=(l>>4)*8+j]
//   D: lane l, reg r: col(c)=l&15, row(n)=(l>>4)*4+r
// Grid (KS, 32): x = k-slice (XCD co-location: linear id % 8 = x % 8 when
// gridDim.x%8==0), y = 128-row tile.
__global__ __launch_bounds__(256, 2)
void bilinear_main(const float* __restrict__ b1f,
                   const float* __restrict__ b2f,
                   const char* __restrict__ Wt,
                   const float* __restrict__ biasg,
                   float* __restrict__ P,
                   float* __restrict__ outd,
                   int klen)
{
  const int tid  = threadIdx.x;
  const int w    = tid >> 6;
  const int l    = tid & 63;
  const int l15  = l & 15;
  const int quad = l >> 4;
  const int mhalf = w & 1;
  const int chalf = w >> 1;
  const bool cfull = (chalf == 0);   // chalf=1 waves skip ct==3 (zero pad)
  const int bm = blockIdx.y;
  const int k0 = blockIdx.x * klen;

  int nrow[4];
#pragma unroll
  for (int rt = 0; rt < 4; ++rt) nrow[rt] = bm * 128 + mhalf * 64 + rt * 16 + l15;

  // Lane-fixed Wt base for this block's k-range.
  const char* wtl = Wt + (size_t)(k0 >> 5) * 8192
                       + (chalf * 64 + l15) * 64 + quad * 16;

  floatx4 acc[4][4];
#pragma unroll
  for (int rt = 0; rt < 4; ++rt)
#pragma unroll
    for (int ct = 0; ct < 4; ++ct)
      acc[rt][ct] = floatx4{0.f, 0.f, 0.f, 0.f};

  // f32 cache of b2[nrow[rt], kblk*64 + kh*32 + quad*8 + e], e=0..7.
  // 64 VGPRs, reloaded once per kblk (amortized over 64 windows).
  float b2r[4][2][8];
  int cur_k = -1;
  const int nwin = klen >> 6;

  for (int gwin = 0; gwin < nwin; gwin += 8) {
    const int kap0 = k0 + (gwin << 6);
    const int kblk = kap0 >> 12;
    const int i0   = (kap0 >> 6) & 63;
    if (kblk != cur_k) {
      cur_k = kblk;
#pragma unroll
      for (int rt = 0; rt < 4; ++rt)
#pragma unroll
        for (int kh = 0; kh < 2; ++kh) {
          const float* p = b2f + (size_t)nrow[rt] * EMB + kblk * 64 + kh * 32 + quad * 8;
          float4 v0 = ((const float4*)p)[0];
          float4 v1 = ((const float4*)p)[1];
          b2r[rt][kh][0] = v0.x; b2r[rt][kh][1] = v0.y;
          b2r[rt][kh][2] = v0.z; b2r[rt][kh][3] = v0.w;
          b2r[rt][kh][4] = v1.x; b2r[rt][kh][5] = v1.y;
          b2r[rt][kh][6] = v1.z; b2r[rt][kh][7] = v1.w;
        }
    }

    // Two half-groups of 4 windows; b1 window-scalars live as f32 float4
    // (selection by compile-time ii2 -> zero VALU for broadcast build).
#pragma unroll
    for (int ih = 0; ih < 2; ++ih) {
      float4 b1v[4];
#pragma unroll
      for (int rt = 0; rt < 4; ++rt)
        b1v[rt] = *(const float4*)(b1f + (size_t)nrow[rt] * EMB +
                                   kblk * 64 + i0 + ih * 4);

#pragma unroll
      for (int ii2 = 0; ii2 < 4; ++ii2) {
        const int iw = gwin + ih * 4 + ii2;
        // This window's Wt pointer: k-chunks iw*2 and iw*2+1.
        const char* pw = wtl + (size_t)iw * 16384;

        float s[4];
#pragma unroll
        for (int rt = 0; rt < 4; ++rt)
          s[rt] = (&b1v[rt].x)[ii2];

#pragma unroll
        for (int kh = 0; kh < 2; ++kh) {
          // Coalesced B-fragment loads (16B/lane from a 1KB-contig region);
          // ct==3 is the zero class-pad for chalf==1 -> skip (wave-uniform).
          short8 wf[4];
#pragma unroll
          for (int ct = 0; ct < 4; ++ct)
            if (ct < 3 || cfull)
              wf[ct] = __builtin_bit_cast(short8,
                         *(const uint4*)(pw + kh * 8192 + ct * 1024));
          // A fragment for this kh, per rt: f32 mul + pack (3 insts/dword).
#pragma unroll
          for (int rt = 0; rt < 4; ++rt) {
            uint4 afr;
            afr.x = mkbf2(b2r[rt][kh][0] * s[rt], b2r[rt][kh][1] * s[rt]);
            afr.y = mkbf2(b2r[rt][kh][2] * s[rt], b2r[rt][kh][3] * s[rt]);
            afr.z = mkbf2(b2r[rt][kh][4] * s[rt], b2r[rt][kh][5] * s[rt]);
            afr.w = mkbf2(b2r[rt][kh][6] * s[rt], b2r[rt][kh][7] * s[rt]);
            short8 af = __builtin_bit_cast(short8, afr);
#pragma unroll
            for (int ct = 0; ct < 4; ++ct)
              if (ct < 3 || cfull)
                acc[rt][ct] = __builtin_amdgcn_mfma_f32_16x16x32_bf16(
                                  af, wf[ct], acc[rt][ct], 0, 0, 0);
          }
        }
      }
    }
  }

  // Epilogue. D: col(c)=l15, row(n)=quad*4+r within each 16x16 tile.
  if (P) {
    float* Pb = P + (size_t)blockIdx.x * OUT_ELEMS;   // slice = blockIdx.x
#pragma unroll
    for (int rt = 0; rt < 4; ++rt)
#pragma unroll
      for (int ct = 0; ct < 4; ++ct) {
        const int c = chalf * 64 + ct * 16 + l15;
        if (c < NCLS) {
#pragma unroll
          for (int r = 0; r < 4; ++r) {
            const int row = bm * 128 + mhalf * 64 + rt * 16 + quad * 4 + r;
            Pb[(size_t)row * NCLS + c] = acc[rt][ct][r];
          }
        }
      }
  } else {
#pragma unroll
    for (int rt = 0; rt < 4; ++rt)
#pragma unroll
      for (int ct = 0; ct < 4; ++ct) {
        const int c = chalf * 64 + ct * 16 + l15;
        if (c < NCLS) {
          const float bv = biasg[c];
#pragma unroll
          for (int r = 0; r < 4; ++r) {
            const int row = bm * 128 + mhalf * 64 + rt * 16 + quad * 4 + r;
            outd[(size_t)row * NCLS + c] = acc[rt][ct][r] + bv;
          }
        }
      }
  }
}

// Sum KS partial slices + f32 bias -> f32 output. float4-vectorized.
// KS templated so the accumulation loop fully unrolls (runtime bound left a
// dependent load->add chain, one L2 latency per slice).
template<int KSC>
__global__ void reduce_bias_t(const float* __restrict__ P,
                              const float* __restrict__ biasg,
                              float* __restrict__ out)
{
  int i = blockIdx.x * blockDim.x + threadIdx.x;
  const int n4 = OUT_ELEMS / 4;           // 99328
  if (i >= n4) return;
  int c0 = (i * 4) % NCLS;
  int c1 = c0 + 1 == NCLS ? 0 : c0 + 1;
  int c2 = c1 + 1 == NCLS ? 0 : c1 + 1;
  int c3 = c2 + 1 == NCLS ? 0 : c2 + 1;
  float4 s;
  s.x = biasg[c0]; s.y = biasg[c1]; s.z = biasg[c2]; s.w = biasg[c3];
  const float4* P4 = (const float4*)P;
#pragma unroll
  for (int t = 0; t < KSC; ++t) {
    float4 v = P4[(size_t)t * n4 + i];
    s.x += v.x; s.y += v.y; s.z += v.z; s.w += v.w;
  }
  ((float4*)out)[i] = s;
}

static void launch_reduce(int KS, const float* P, const float* bb, float* out,
                          hipStream_t stream) {
  const int nb = (OUT_ELEMS / 4 + 255) / 256;
  switch (KS) {
    case 16: reduce_bias_t<16><<<nb, 256, 0, stream>>>(P, bb, out); break;
    case 12: reduce_bias_t<12><<<nb, 256, 0, stream>>>(P, bb, out); break;
    case 8:  reduce_bias_t<8><<<nb, 256, 0, stream>>>(P, bb, out);  break;
    case 6:  reduce_bias_t<6><<<nb, 256, 0, stream>>>(P, bb, out);  break;
    case 4:  reduce_bias_t<4><<<nb, 256, 0, stream>>>(P, bb, out);  break;
    case 3:  reduce_bias_t<3><<<nb, 256, 0, stream>>>(P, bb, out);  break;
    case 2:  reduce_bias_t<2><<<nb, 256, 0, stream>>>(P, bb, out);  break;
    default: reduce_bias_t<1><<<nb, 256, 0, stream>>>(P, bb, out);  break;
  }
}

extern "C" void kernel_launch(void* const* d_in, const int* in_sizes, int n_in,
                              void* d_out, int out_size, void* d_ws, size_t ws_size,
                              hipStream_t stream) {
  const float* b1f = (const float*)d_in[0];   // [4096,768] f32
  const float* b2f = (const float*)d_in[1];   // [4096,768] f32
  const float* Wf  = (const float*)d_in[2];   // [97, 49152] f32
  const float* bbf = (const float*)d_in[3];   // [97] f32
  float* out = (float*)d_out;

  const size_t slice = (size_t)OUT_ELEMS * 4;     // 1,589,248
  // klen = KTOT/KS must be a multiple of 512 -> KS divides 96.
  // KS=16 -> grid 512 blocks = exactly 2 blocks/CU (reg-capped 2 waves/SIMD).
  static const int cands[] = {16, 12, 8, 6, 4, 3, 2, 1};
  const int NC = 8;

  // Workspace plan: [Wt | P].
  int KS = 0;
  for (int i = 0; i < NC; ++i)
    if (WT_BYTES + (size_t)cands[i] * slice <= ws_size) { KS = cands[i]; break; }

  uint4* Wt = (uint4*)d_ws;
  const int nwt = NK32 * 128 * 4;

  prep<<<(nwt + 255) / 256, 256, 0, stream>>>(Wf, Wt);

  if (KS > 0) {
    float* P = (float*)((char*)d_ws + WT_BYTES);
    bilinear_main<<<dim3(KS, 32), 256, 0, stream>>>(
        b1f, b2f, (const char*)Wt, bbf, P, nullptr, KTOT / KS);
    launch_reduce(KS, P, bbf, out, stream);
  } else {
    // Minimal-workspace fallback: single slice, direct f32 output.
    bilinear_main<<<dim3(1, 32), 256, 0, stream>>>(
        b1f, b2f, (const char*)Wt, bbf, nullptr, out, KTOT);
  }
}

// Round 6
// 151.882 us; speedup vs baseline: 1.0727x; 1.0061x over previous
//
#include <hip/hip_runtime.h>
#include <hip/hip_bf16.h>
#include <stdint.h>

// Problem constants
#define NROWS 4096
#define NCLS  97
#define EMB   768
#define KTOT  49152                 // EMB * 64
#define OUT_ELEMS (NROWS * NCLS)    // 397312
#define E_ELEMS  (NROWS * EMB)      // 3,145,728
#define NK32  (KTOT / 32)           // 1536 k-chunks of 32
#define WT_BYTES ((size_t)NK32 * 128 * 64)   // 12,582,912 (Wt: [kc][c<128][32] f16)

typedef __attribute__((ext_vector_type(4)))  float floatx4;
typedef _Float16 f16x2 __attribute__((ext_vector_type(2)));
typedef _Float16 f16x8 __attribute__((ext_vector_type(8)));

// Pack 8 f32 -> 8 f16 (RNE via scalar casts) as a uint4.
__device__ __forceinline__ uint4 cvt8h(float4 a, float4 b) {
  f16x8 v;
  v[0] = (_Float16)a.x; v[1] = (_Float16)a.y; v[2] = (_Float16)a.z; v[3] = (_Float16)a.w;
  v[4] = (_Float16)b.x; v[5] = (_Float16)b.y; v[6] = (_Float16)b.z; v[7] = (_Float16)b.w;
  return __builtin_bit_cast(uint4, v);
}

// Prep: build Wt (W transposed into MFMA B-fragment order, f16, classes
// padded to 128 with zeros). b1/b2 are consumed in f32 directly.
// Wt 16B-chunk t: eo=t&3 (8-elem octet), c=(t>>2)&127, kc=t>>9:
//   Wt byte addr = kc*8192 + c*64 + eo*16  <-> W[c][kc*32 + eo*8 .. +7]
__global__ void prep(const float* __restrict__ W, uint4* __restrict__ wt)
{
  const int nwt = NK32 * 128 * 4;      // 786,432
  int t = blockIdx.x * blockDim.x + threadIdx.x;
  if (t >= nwt) return;
  int eo = t & 3;
  int c  = (t >> 2) & 127;
  int kc = t >> 9;
  uint4 v = uint4{0u, 0u, 0u, 0u};
  if (c < NCLS) {
    const float4* p = (const float4*)(W + (size_t)c * KTOT + kc * 32 + eo * 8);
    v = cvt8h(p[0], p[1]);
  }
  wt[t] = v;
}

// Fused on-the-fly-A GEMM, R15.
// R14 counters: 2104 cyc/window-slot/SIMD = MFMA 505 + VALU 526 + ~1070 DEAD
// (neither pipe issues). BW is trivially fine (Wt slice L2-resident per XCD)
// -> dead time is unhidden L2 latency: compiler emits the 7 Wt loads
// just-in-time per window, pays vmcnt wait each kh; 2 waves/SIMD can't
// cover it. Fix both terms:
//  (1) Register ping-pong prefetch: window i+1's Wt fragments (wfB/wfA,
//      compile-time parity in the unrolled 8-window body) are ISSUED before
//      window i's MFMAs -> counted vmcnt, ~600 cyc of compute hides L2.
//  (2) bf16 -> f16: v_pk_mul_f16 is NATIVE (bf16 mul is emulated). A-build
//      = 4 pk_mul per rt*kh + b1 cvt/broadcast ~ 50 VALU/window (was ~260).
//      mfma_f32_16x16x32_f16 = same shape/rate; f16 has MORE mantissa than
//      bf16 so absmax should not grow; accum stays f32.
// Geometry kept: rt=4 (each Wt fragment feeds 4 MFMAs), KS=16, grid (16,32)
// = 2 blocks/CU, launch_bounds(256,2); ct==3 zero-pad tile skipped by
// chalf==1 waves. Regs ~150 VGPR + 64 AGPR = ~214 <= 256 (2 waves/SIMD).
// MFMA 16x16x32 verified triple (bf16-verified; f16 same layout):
//   A: lane l holds A[m=l&15][k=(l>>4)*8+j]; B: W[c=l&15][k=(l>>4)*8+j]
//   D: lane l, reg r: col(c)=l&15, row(n)=(l>>4)*4+r
// Grid (KS, 32): x = k-slice (XCD co-location: linear id % 8 = x % 8 when
// gridDim.x%8==0), y = 128-row tile.
__global__ __launch_bounds__(256, 2)
void bilinear_main(const float* __restrict__ b1f,
                   const float* __restrict__ b2f,
                   const char* __restrict__ Wt,
                   const float* __restrict__ biasg,
                   float* __restrict__ P,
                   float* __restrict__ outd,
                   int klen)
{
  const int tid  = threadIdx.x;
  const int w    = tid >> 6;
  const int l    = tid & 63;
  const int l15  = l & 15;
  const int quad = l >> 4;
  const int mhalf = w & 1;
  const int chalf = w >> 1;
  const bool cfull = (chalf == 0);   // chalf=1 waves skip ct==3 (zero pad)
  const int bm = blockIdx.y;
  const int k0 = blockIdx.x * klen;

  int nrow[4];
#pragma unroll
  for (int rt = 0; rt < 4; ++rt) nrow[rt] = bm * 128 + mhalf * 64 + rt * 16 + l15;

  // Lane-fixed Wt base for this block's k-range.
  const char* wtl = Wt + (size_t)(k0 >> 5) * 8192
                       + (chalf * 64 + l15) * 64 + quad * 16;

  floatx4 acc[4][4];
#pragma unroll
  for (int rt = 0; rt < 4; ++rt)
#pragma unroll
    for (int ct = 0; ct < 4; ++ct)
      acc[rt][ct] = floatx4{0.f, 0.f, 0.f, 0.f};

  // f16-pair cache of b2[nrow[rt], kblk*64 + kh*32 + quad*8 + 2j,2j+1].
  // 32 VGPRs, rebuilt once per kblk (amortized over 64 windows).
  f16x2 b2h[4][2][4];
  f16x2 sv[4];
  uint4 wfA[2][4], wfB[2][4];   // Wt fragment ping-pong [kh][ct]

#define LOADWF(buf, iwv)  do {                                              \
    const char* pw_ = wtl + (size_t)(iwv) * 16384;                          \
    _Pragma("unroll")                                                       \
    for (int kh_ = 0; kh_ < 2; ++kh_)                                       \
      _Pragma("unroll")                                                     \
      for (int ct_ = 0; ct_ < 4; ++ct_)                                     \
        if (ct_ < 3 || cfull)                                               \
          buf[kh_][ct_] = *(const uint4*)(pw_ + kh_ * 8192 + ct_ * 1024);   \
  } while (0)

#define COMPUTE(buf)  do {                                                  \
    _Pragma("unroll")                                                       \
    for (int kh_ = 0; kh_ < 2; ++kh_) {                                     \
      _Pragma("unroll")                                                     \
      for (int rt_ = 0; rt_ < 4; ++rt_) {                                   \
        f16x2 p0 = sv[rt_] * b2h[rt_][kh_][0];                              \
        f16x2 p1 = sv[rt_] * b2h[rt_][kh_][1];                              \
        f16x2 p2 = sv[rt_] * b2h[rt_][kh_][2];                              \
        f16x2 p3 = sv[rt_] * b2h[rt_][kh_][3];                              \
        uint4 au;                                                           \
        au.x = __builtin_bit_cast(uint32_t, p0);                            \
        au.y = __builtin_bit_cast(uint32_t, p1);                            \
        au.z = __builtin_bit_cast(uint32_t, p2);                            \
        au.w = __builtin_bit_cast(uint32_t, p3);                            \
        f16x8 af = __builtin_bit_cast(f16x8, au);                           \
        _Pragma("unroll")                                                   \
        for (int ct_ = 0; ct_ < 4; ++ct_)                                   \
          if (ct_ < 3 || cfull)                                             \
            acc[rt_][ct_] = __builtin_amdgcn_mfma_f32_16x16x32_f16(         \
                af, __builtin_bit_cast(f16x8, buf[kh_][ct_]),               \
                acc[rt_][ct_], 0, 0, 0);                                    \
      }                                                                     \
    }                                                                       \
  } while (0)

  int cur_k = -1;
  const int nwin = klen >> 6;

  // Prologue: window 0 into wfA.
  LOADWF(wfA, 0);

  for (int gwin = 0; gwin < nwin; gwin += 8) {
    const int kap0 = k0 + (gwin << 6);
    const int kblk = kap0 >> 12;
    const int i0   = (kap0 >> 6) & 63;
    if (kblk != cur_k) {
      cur_k = kblk;
#pragma unroll
      for (int rt = 0; rt < 4; ++rt)
#pragma unroll
        for (int kh = 0; kh < 2; ++kh) {
          const float* p = b2f + (size_t)nrow[rt] * EMB + kblk * 64 + kh * 32 + quad * 8;
          float4 v0 = ((const float4*)p)[0];
          float4 v1 = ((const float4*)p)[1];
          b2h[rt][kh][0][0] = (_Float16)v0.x; b2h[rt][kh][0][1] = (_Float16)v0.y;
          b2h[rt][kh][1][0] = (_Float16)v0.z; b2h[rt][kh][1][1] = (_Float16)v0.w;
          b2h[rt][kh][2][0] = (_Float16)v1.x; b2h[rt][kh][2][1] = (_Float16)v1.y;
          b2h[rt][kh][3][0] = (_Float16)v1.z; b2h[rt][kh][3][1] = (_Float16)v1.w;
        }
    }

#pragma unroll
    for (int ih = 0; ih < 2; ++ih) {
      float4 b1v[4];
#pragma unroll
      for (int rt = 0; rt < 4; ++rt)
        b1v[rt] = *(const float4*)(b1f + (size_t)nrow[rt] * EMB +
                                   kblk * 64 + i0 + ih * 4);

#pragma unroll
      for (int ii2 = 0; ii2 < 4; ++ii2) {
        const int s  = ih * 4 + ii2;       // compile-time slot 0..7
        const int iw = gwin + s;
        int ipf = iw + 1;                   // prefetch window (clamp at end:
        if (ipf > nwin - 1) ipf = nwin - 1; //  harmless duplicate load)

        // b1 window scalar -> f16 broadcast pair (cvt + pack, 2 ops/rt).
#pragma unroll
        for (int rt = 0; rt < 4; ++rt) {
          _Float16 h = (_Float16)((&b1v[rt].x)[ii2]);
          sv[rt][0] = h; sv[rt][1] = h;
        }

        // Issue next window's Wt loads BEFORE this window's MFMAs
        // (counted vmcnt keeps them in flight across the compute).
        if ((s & 1) == 0) { LOADWF(wfB, ipf); COMPUTE(wfA); }
        else              { LOADWF(wfA, ipf); COMPUTE(wfB); }
      }
    }
  }
#undef LOADWF
#undef COMPUTE

  // Epilogue. D: col(c)=l15, row(n)=quad*4+r within each 16x16 tile.
  if (P) {
    float* Pb = P + (size_t)blockIdx.x * OUT_ELEMS;   // slice = blockIdx.x
#pragma unroll
    for (int rt = 0; rt < 4; ++rt)
#pragma unroll
      for (int ct = 0; ct < 4; ++ct) {
        const int c = chalf * 64 + ct * 16 + l15;
        if (c < NCLS) {
#pragma unroll
          for (int r = 0; r < 4; ++r) {
            const int row = bm * 128 + mhalf * 64 + rt * 16 + quad * 4 + r;
            Pb[(size_t)row * NCLS + c] = acc[rt][ct][r];
          }
        }
      }
  } else {
#pragma unroll
    for (int rt = 0; rt < 4; ++rt)
#pragma unroll
      for (int ct = 0; ct < 4; ++ct) {
        const int c = chalf * 64 + ct * 16 + l15;
        if (c < NCLS) {
          const float bv = biasg[c];
#pragma unroll
          for (int r = 0; r < 4; ++r) {
            const int row = bm * 128 + mhalf * 64 + rt * 16 + quad * 4 + r;
            outd[(size_t)row * NCLS + c] = acc[rt][ct][r] + bv;
          }
        }
      }
  }
}

// Sum KS partial slices + f32 bias -> f32 output. float4-vectorized.
// KS templated so the accumulation loop fully unrolls (runtime bound left a
// dependent load->add chain, one L2 latency per slice).
template<int KSC>
__global__ void reduce_bias_t(const float* __restrict__ P,
                              const float* __restrict__ biasg,
                              float* __restrict__ out)
{
  int i = blockIdx.x * blockDim.x + threadIdx.x;
  const int n4 = OUT_ELEMS / 4;           // 99328
  if (i >= n4) return;
  int c0 = (i * 4) % NCLS;
  int c1 = c0 + 1 == NCLS ? 0 : c0 + 1;
  int c2 = c1 + 1 == NCLS ? 0 : c1 + 1;
  int c3 = c2 + 1 == NCLS ? 0 : c2 + 1;
  float4 s;
  s.x = biasg[c0]; s.y = biasg[c1]; s.z = biasg[c2]; s.w = biasg[c3];
  const float4* P4 = (const float4*)P;
#pragma unroll
  for (int t = 0; t < KSC; ++t) {
    float4 v = P4[(size_t)t * n4 + i];
    s.x += v.x; s.y += v.y; s.z += v.z; s.w += v.w;
  }
  ((float4*)out)[i] = s;
}

static void launch_reduce(int KS, const float* P, const float* bb, float* out,
                          hipStream_t stream) {
  const int nb = (OUT_ELEMS / 4 + 255) / 256;
  switch (KS) {
    case 16: reduce_bias_t<16><<<nb, 256, 0, stream>>>(P, bb, out); break;
    case 12: reduce_bias_t<12><<<nb, 256, 0, stream>>>(P, bb, out); break;
    case 8:  reduce_bias_t<8><<<nb, 256, 0, stream>>>(P, bb, out);  break;
    case 6:  reduce_bias_t<6><<<nb, 256, 0, stream>>>(P, bb, out);  break;
    case 4:  reduce_bias_t<4><<<nb, 256, 0, stream>>>(P, bb, out);  break;
    case 3:  reduce_bias_t<3><<<nb, 256, 0, stream>>>(P, bb, out);  break;
    case 2:  reduce_bias_t<2><<<nb, 256, 0, stream>>>(P, bb, out);  break;
    default: reduce_bias_t<1><<<nb, 256, 0, stream>>>(P, bb, out);  break;
  }
}

extern "C" void kernel_launch(void* const* d_in, const int* in_sizes, int n_in,
                              void* d_out, int out_size, void* d_ws, size_t ws_size,
                              hipStream_t stream) {
  const float* b1f = (const float*)d_in[0];   // [4096,768] f32
  const float* b2f = (const float*)d_in[1];   // [4096,768] f32
  const float* Wf  = (const float*)d_in[2];   // [97, 49152] f32
  const float* bbf = (const float*)d_in[3];   // [97] f32
  float* out = (float*)d_out;

  const size_t slice = (size_t)OUT_ELEMS * 4;     // 1,589,248
  // klen = KTOT/KS must be a multiple of 512 -> KS divides 96.
  // KS=16 -> grid 512 blocks = exactly 2 blocks/CU (reg-capped 2 waves/SIMD).
  static const int cands[] = {16, 12, 8, 6, 4, 3, 2, 1};
  const int NC = 8;

  // Workspace plan: [Wt | P].
  int KS = 0;
  for (int i = 0; i < NC; ++i)
    if (WT_BYTES + (size_t)cands[i] * slice <= ws_size) { KS = cands[i]; break; }

  uint4* Wt = (uint4*)d_ws;
  const int nwt = NK32 * 128 * 4;

  prep<<<(nwt + 255) / 256, 256, 0, stream>>>(Wf, Wt);

  if (KS > 0) {
    float* P = (float*)((char*)d_ws + WT_BYTES);
    bilinear_main<<<dim3(KS, 32), 256, 0, stream>>>(
        b1f, b2f, (const char*)Wt, bbf, P, nullptr, KTOT / KS);
    launch_reduce(KS, P, bbf, out, stream);
  } else {
    // Minimal-workspace fallback: single slice, direct f32 output.
    bilinear_main<<<dim3(1, 32), 256, 0, stream>>>(
        b1f, b2f, (const char*)Wt, bbf, nullptr, out, KTOT);
  }
}